// Round 4
// baseline (2155.418 us; speedup 1.0000x reference)
//
#include <hip/hip_runtime.h>

// GRU recurrence, fused persistent kernel (round 4).
// Round-3 passed (absmax 0.0039) but was latency-serialized: 39K cyc/step, all
// pipes <4% busy. This round: (1) batched weight loads (36 x 16B in flight per
// u-tile, 256-VGPR budget), (2) f32 carry in registers (same-lane write/read),
// (3) XOR-swizzled unpadded LDS h tiles, (4) x(t+1) prefetch, (5) fast div.

typedef __attribute__((ext_vector_type(8))) short short8;   // 8 x bf16 MFMA frag
typedef __attribute__((ext_vector_type(4))) float f32x4;

constexpr int B_ = 1024, T_ = 128, I_ = 128, H_ = 256, OUT_ = 64;
constexpr int ROWS = 16;        // batch rows per block
constexpr int NBLK = B_ / ROWS; // 64 blocks

#define DEVI __device__ __forceinline__

DEVI unsigned short f2b(float f) {  // RNE float->bf16 (finite values only here)
    unsigned u = __builtin_bit_cast(unsigned, f);
    u += 0x7fffu + ((u >> 16) & 1u);
    return (unsigned short)(u >> 16);
}
DEVI float sigmoidf_(float x) { float e = __expf(-x); return __fdividef(1.f, 1.f + e); }
DEVI float tanhf_(float x) { float e = __expf(2.f * x); return __fdividef(e - 1.f, e + 1.f); }

DEVI short8 ldg8(const unsigned short* p) {   // 8 bf16 = one 16B load
    return __builtin_bit_cast(short8, *reinterpret_cast<const uint4*>(p));
}
DEVI short8 cvt8(const float* p) {            // 8 f32 -> bf16 fragment
    f32x4 lo = *reinterpret_cast<const f32x4*>(p);
    f32x4 hi = *reinterpret_cast<const f32x4*>(p + 4);
    union { unsigned short s[8]; short8 v; } r;
#pragma unroll
    for (int e = 0; e < 4; ++e) { r.s[e] = f2b(lo[e]); r.s[4 + e] = f2b(hi[e]); }
    return r.v;
}
DEVI f32x4 mfma(short8 a, short8 b, f32x4 c) {
    return __builtin_amdgcn_mfma_f32_16x16x32_bf16(a, b, c, 0, 0, 0);
}

// XOR-swizzled addressing into a [16][256] bf16 LDS tile (row-major, unpadded).
// byte ^= (row&7)<<4 : spreads the 16 rows' 16B-granules across all 8 bank-groups.
DEVI unsigned short* swz(unsigned short* base, int row, int col) {
    int byte = (row * H_ + col) * 2;
    byte ^= (row & 7) << 4;
    return (unsigned short*)((char*)base + byte);
}
DEVI const unsigned short* swzc(const unsigned short* base, int row, int col) {
    int byte = (row * H_ + col) * 2;
    byte ^= (row & 7) << 4;
    return (const unsigned short*)((const char*)base + byte);
}

// ---- weight pre-conversion: f32 -> bf16 into d_ws (n % 8 == 0) ----
__global__ void cvt_w(const float* __restrict__ src, unsigned short* __restrict__ dst, int n) {
    int i = (blockIdx.x * blockDim.x + threadIdx.x) * 8;
    if (i >= n) return;
    f32x4 lo = *reinterpret_cast<const f32x4*>(src + i);
    f32x4 hi = *reinterpret_cast<const f32x4*>(src + i + 4);
    union { unsigned short s[8]; uint4 v; } r;
#pragma unroll
    for (int e = 0; e < 4; ++e) { r.s[e] = f2b(lo[e]); r.s[4 + e] = f2b(hi[e]); }
    *reinterpret_cast<uint4*>(dst + i) = r.v;
}

__global__ __launch_bounds__(512, 2) void gru_fused(
    const float* __restrict__ s0,             // [B][H] f32
    const float* __restrict__ a,              // [B][T][I] f32
    const unsigned short* __restrict__ w_ih,  // [3H][I] bf16 (ws)  rows: r,z,n
    const unsigned short* __restrict__ w_hh,  // [3H][H] bf16 (ws)
    const unsigned short* __restrict__ w_rw,  // [OUT][H] bf16 (ws)
    const unsigned short* __restrict__ w_st,  // [H][H] bf16 (ws)
    float* __restrict__ out_r,                // [T][OUT] f32
    float* __restrict__ out_s)                // [B][T][H] f32
{
    __shared__ unsigned short h16[ROWS * H_];   // carry h, bf16 (swizzled)
    __shared__ unsigned short hn16[ROWS * H_];  // h_new, bf16 (swizzled)

    const int tid = threadIdx.x;
    const int w = tid >> 6;     // wave 0..7
    const int l = tid & 63;
    const int m = l & 15;       // MFMA A row / B col within tile
    const int kg = l >> 4;      // k-group 0..3 (8 contiguous k each)
    const int R0 = blockIdx.x * ROWS;
    const int pr = tid >> 5;          // init: row 0..15
    const int pc = (tid & 31) * 8;    // init: col 0..248 step 8

    // f32 carry in registers: hreg[u][v] = h[kg*4+v][(2w+u)*16+m]
    // (phase-2 writer lane == phase-1 reader lane for each (row,col))
    float hreg[2][4];
#pragma unroll
    for (int u = 0; u < 2; ++u)
#pragma unroll
        for (int v = 0; v < 4; ++v)
            hreg[u][v] = s0[(size_t)(R0 + kg * 4 + v) * H_ + (2 * w + u) * 16 + m];

    // bf16 shadow of h
    *reinterpret_cast<uint4*>(swz(h16, pr, pc)) =
        __builtin_bit_cast(uint4, cvt8(&s0[(size_t)(R0 + pr) * H_ + pc]));
    __syncthreads();

    // x fragments for t=0
    short8 xa[4];
    {
        const float* xr = a + (size_t)(R0 + m) * T_ * I_ + kg * 8;
#pragma unroll
        for (int kt = 0; kt < 4; ++kt) xa[kt] = cvt8(xr + kt * 32);
    }

    for (int t = 0; t < T_; ++t) {
        // ---- phase 1: gate GEMMs + in-register GRU elementwise -> hn16 ----
        short8 ha[8];
#pragma unroll
        for (int kt = 0; kt < 8; ++kt)
            ha[kt] = ldg8(swzc(h16, m, kt * 32 + kg * 8));

#pragma unroll
        for (int u = 0; u < 2; ++u) {
            const int gcol = (2 * w + u) * 16 + m;   // gate index 0..255
            // batch ALL weight loads for this u-tile first (36 x 16B in flight)
            short8 wi[12], wh[24];
            {
                const unsigned short* p0 = w_ih + (size_t)gcol * I_ + kg * 8;
#pragma unroll
                for (int kt = 0; kt < 4; ++kt) {
                    wi[kt]     = ldg8(p0 + kt * 32);
                    wi[4 + kt] = ldg8(p0 + 256 * I_ + kt * 32);
                    wi[8 + kt] = ldg8(p0 + 512 * I_ + kt * 32);
                }
                const unsigned short* p1 = w_hh + (size_t)gcol * H_ + kg * 8;
#pragma unroll
                for (int kt = 0; kt < 8; ++kt) {
                    wh[kt]      = ldg8(p1 + kt * 32);
                    wh[8 + kt]  = ldg8(p1 + 256 * H_ + kt * 32);
                    wh[16 + kt] = ldg8(p1 + 512 * H_ + kt * 32);
                }
            }
            f32x4 ar  = {0.f, 0.f, 0.f, 0.f};
            f32x4 az  = {0.f, 0.f, 0.f, 0.f};
            f32x4 ani = {0.f, 0.f, 0.f, 0.f};
            f32x4 anh = {0.f, 0.f, 0.f, 0.f};
#pragma unroll
            for (int kt = 0; kt < 4; ++kt) {   // x part, K=128
                ar  = mfma(xa[kt], wi[kt],     ar);
                az  = mfma(xa[kt], wi[4 + kt], az);
                ani = mfma(xa[kt], wi[8 + kt], ani);
            }
            if (u == 1) {  // xa dead now: prefetch x for t+1 (overlaps h-MFMAs/phase2)
                const int tn = (t + 1 < T_) ? t + 1 : t;
                const float* xr = a + ((size_t)(R0 + m) * T_ + tn) * I_ + kg * 8;
#pragma unroll
                for (int kt = 0; kt < 4; ++kt) xa[kt] = cvt8(xr + kt * 32);
            }
#pragma unroll
            for (int kt = 0; kt < 8; ++kt) {   // h part, K=256
                ar  = mfma(ha[kt], wh[kt],      ar);
                az  = mfma(ha[kt], wh[8 + kt],  az);
                anh = mfma(ha[kt], wh[16 + kt], anh);
            }
            // D mapping: row = kg*4+v (batch), col = m -> gate gcol
#pragma unroll
            for (int v = 0; v < 4; ++v) {
                const float rg = sigmoidf_(ar[v]);
                const float zg = sigmoidf_(az[v]);
                const float ng = tanhf_(ani[v] + rg * anh[v]);
                *swz(hn16, kg * 4 + v, gcol) = f2b((1.f - zg) * ng + zg * hreg[u][v]);
            }
        }
        __syncthreads();

        // ---- phase 2: s_next = sig(h_new @ w_state^T) -> regs + h16 + out_s ----
        short8 na[8];
#pragma unroll
        for (int kt = 0; kt < 8; ++kt)
            na[kt] = ldg8(swzc(hn16, m, kt * 32 + kg * 8));
#pragma unroll
        for (int u = 0; u < 2; ++u) {
            const int j = (2 * w + u) * 16 + m;  // state col 0..255
            short8 wsb[8];
            const unsigned short* p = w_st + (size_t)j * H_ + kg * 8;
#pragma unroll
            for (int kt = 0; kt < 8; ++kt) wsb[kt] = ldg8(p + kt * 32);
            f32x4 acc = {0.f, 0.f, 0.f, 0.f};
#pragma unroll
            for (int kt = 0; kt < 8; ++kt) acc = mfma(na[kt], wsb[kt], acc);
#pragma unroll
            for (int v = 0; v < 4; ++v) {
                const int row = kg * 4 + v;
                const float s = sigmoidf_(acc[v]);
                hreg[u][v] = s;                                      // f32 carry
                *swz(h16, row, j) = f2b(s);                          // bf16 shadow
                out_s[((size_t)(R0 + row) * T_ + t) * H_ + j] = s;   // 64B segments
            }
        }
        if (blockIdx.x == 0 && w < 4) {  // r_t = sig(h_new[0] @ w_reward^T)
            const int o = w * 16 + m;    // 0..63
            f32x4 acc = {0.f, 0.f, 0.f, 0.f};
            const unsigned short* p = w_rw + (size_t)o * H_ + kg * 8;
#pragma unroll
            for (int kt = 0; kt < 8; ++kt)
                acc = mfma(na[kt], ldg8(p + kt * 32), acc);
            if (kg == 0)  // batch row 0 = D row 0 = lanes 0..15, reg 0
                out_r[t * OUT_ + o] = sigmoidf_(acc[0]);
        }
        __syncthreads();
    }
}

extern "C" void kernel_launch(void* const* d_in, const int* in_sizes, int n_in,
                              void* d_out, int out_size, void* d_ws, size_t ws_size,
                              hipStream_t stream) {
    const float* s0  = (const float*)d_in[0];
    const float* a   = (const float*)d_in[1];
    const float* wih = (const float*)d_in[2];
    const float* whh = (const float*)d_in[3];
    const float* wrw = (const float*)d_in[4];
    const float* wst = (const float*)d_in[5];

    // bf16 weight copies in workspace
    unsigned short* ws16 = (unsigned short*)d_ws;
    unsigned short* wih16 = ws16;                 // 768*128  = 98304
    unsigned short* whh16 = wih16 + 98304;        // 768*256  = 196608
    unsigned short* wrw16 = whh16 + 196608;       // 64*256   = 16384
    unsigned short* wst16 = wrw16 + 16384;        // 256*256  = 65536

    cvt_w<<<98304  / (256 * 8), 256, 0, stream>>>(wih, wih16, 98304);
    cvt_w<<<196608 / (256 * 8), 256, 0, stream>>>(whh, whh16, 196608);
    cvt_w<<<16384  / (256 * 8), 256, 0, stream>>>(wrw, wrw16, 16384);
    cvt_w<<<65536  / (256 * 8), 256, 0, stream>>>(wst, wst16, 65536);

    float* out = (float*)d_out;
    gru_fused<<<NBLK, 512, 0, stream>>>(s0, a, wih16, whh16, wrw16, wst16,
                                        out, out + (size_t)T_ * OUT_);
}